// Round 21
// baseline (61.660 us; speedup 1.0000x reference)
//
#include <hip/hip_runtime.h>
#include <math.h>

#define NFRM  257
#define BATCH 8
#define TLEN  262144          // 2^18
#define PAD   2048
#define TWO_PI 6.2831853071795864769f
#define INVSQRT2 0.70710678118654752440f

#define FPADR 288             // padded frames: 9 m-tiles of 32
#define XPADL 299008          // bf16 padded signal length per (b,ch): 288*1024+4096
#define XVALID 266240         // TLEN + 2*PAD (valid xpad indices)
#define NKS   256             // k-steps of 32
#define KSPL  8               // K splits (each 8 chunks of 128 k = 1024 k)
#define CHPS  8               // chunks per K-split
#define NCOL  80              // 5 ctx groups x 16 (j padded 15->16)
#define GRID  576             // = BATCH * 9 * KSPL
#define NTHR  320

// padded LDS index (float2 units): breaks all 8^s stride bank conflicts
#define PIDX(i) ((i) + ((i) >> 4) + ((i) >> 8))

typedef short bf16x8 __attribute__((ext_vector_type(8)));
typedef float f32x4  __attribute__((ext_vector_type(4)));

__device__ __forceinline__ int reflect_idx(int s) {
    if (s < 0) s = -s;
    if (s >= TLEN) s = 2 * (TLEN - 1) - s;
    return s;
}
__device__ __forceinline__ unsigned short f2bf(float f) {
    unsigned int u = __float_as_uint(f);
    unsigned int r = (u + 0x7FFFu + ((u >> 16) & 1u)) >> 16;   // RTNE
    return (unsigned short)r;
}
__device__ __forceinline__ float2 cmul(float2 a, float2 b) {
    return make_float2(a.x * b.x - a.y * b.y, a.x * b.y + a.y * b.x);
}

// =================== shared phase bodies (used by mega AND fallback) ================

// Phase X: reflect-padded bf16 signal (runs on idle blocks during phase D)
__device__ __forceinline__ void phaseX(int gtid, int gstride,
                                       const float* __restrict__ x,
                                       unsigned short* __restrict__ xbf) {
    const int SPB = XPADL / 8;          // uint4-stores per (b,ch) = 37376
    const int NST = 16 * SPB;           // 598016
    for (int s = gtid; s < NST; s += gstride) {
        int bc = s / SPB;
        int i0 = (s - bc * SPB) * 8;
        const float* sig = x + (size_t)bc * TLEN;
        unsigned short v[8];
#pragma unroll
        for (int e = 0; e < 8; e++) {
            int i = i0 + e;
            float val = 0.f;
            if (i < XVALID) val = sig[reflect_idx(i - PAD)];
            v[e] = f2bf(val);
        }
        uint4 o;
        o.x = (unsigned)v[0] | ((unsigned)v[1] << 16);
        o.y = (unsigned)v[2] | ((unsigned)v[3] << 16);
        o.z = (unsigned)v[4] | ((unsigned)v[5] << 16);
        o.w = (unsigned)v[6] | ((unsigned)v[7] << 16);
        *(uint4*)(xbf + (size_t)bc * XPADL + i0) = o;
    }
}

// Phase D: w1 row (j,g,ch) -> 4096-pt FFT -> windowed FIR taps -> Bwf bf16 records
template<int NT>
__device__ __forceinline__ void phaseD(int blk, int tid, float2* zb,
                                       const float* __restrict__ w1,
                                       unsigned int* __restrict__ Bwf) {
    int ch = blk & 1;
    int jg = blk >> 1;
    int g  = jg % 5;
    int j  = jg / 5;
    int cA = ch, cB = ch + 2;

    for (int bin = tid; bin < 4096; bin += NT) {
        float ar = 0.f, ai = 0.f;
        if (bin <= 2048) {
            ar =  w1[(size_t)(bin * 20 + g * 4 + cA) * 15 + j];
            ai = -w1[(size_t)(bin * 20 + g * 4 + cB) * 15 + j];
        }
        int rev = ((bin & 7) << 9) | (((bin >> 3) & 7) << 6) | (((bin >> 6) & 7) << 3) | ((bin >> 9) & 7);
        zb[PIDX(rev)] = make_float2(ar, ai);
    }
    __syncthreads();

#pragma unroll
    for (int s = 0; s < 4; s++) {
        int E    = 1 << (3 * s);
        int step = 1 << (9 - 3 * s);
        for (int t = tid; t < 512; t += NT) {
            int pos = t & (E - 1);
            int bq  = t >> (3 * s);
            int base = (bq << (3 * s + 3)) + pos;

            float2 a0 = zb[PIDX(base)];
            float2 a1 = zb[PIDX(base + E)];
            float2 a2 = zb[PIDX(base + 2 * E)];
            float2 a3 = zb[PIDX(base + 3 * E)];
            float2 a4 = zb[PIDX(base + 4 * E)];
            float2 a5 = zb[PIDX(base + 5 * E)];
            float2 a6 = zb[PIDX(base + 6 * E)];
            float2 a7 = zb[PIDX(base + 7 * E)];

            if (s > 0) {
                float sv, cv;
                sincosf(-(TWO_PI * (float)(pos * step)) / 4096.0f, &sv, &cv);
                float2 w1t = make_float2(cv, sv);
                float2 w2t = cmul(w1t, w1t);
                float2 w3t = cmul(w2t, w1t);
                float2 w4t = cmul(w2t, w2t);
                float2 w5t = cmul(w3t, w2t);
                float2 w6t = cmul(w3t, w3t);
                float2 w7t = cmul(w4t, w3t);
                a1 = cmul(a1, w1t); a2 = cmul(a2, w2t); a3 = cmul(a3, w3t);
                a4 = cmul(a4, w4t); a5 = cmul(a5, w5t); a6 = cmul(a6, w6t);
                a7 = cmul(a7, w7t);
            }

            float2 t0 = make_float2(a0.x + a4.x, a0.y + a4.y);
            float2 t1 = make_float2(a0.x - a4.x, a0.y - a4.y);
            float2 t2 = make_float2(a2.x + a6.x, a2.y + a6.y);
            float2 t3 = make_float2(a2.x - a6.x, a2.y - a6.y);
            float2 E0 = make_float2(t0.x + t2.x, t0.y + t2.y);
            float2 E2 = make_float2(t0.x - t2.x, t0.y - t2.y);
            float2 E1 = make_float2(t1.x + t3.y, t1.y - t3.x);
            float2 E3 = make_float2(t1.x - t3.y, t1.y + t3.x);
            float2 u0 = make_float2(a1.x + a5.x, a1.y + a5.y);
            float2 u1 = make_float2(a1.x - a5.x, a1.y - a5.y);
            float2 u2 = make_float2(a3.x + a7.x, a3.y + a7.y);
            float2 u3 = make_float2(a3.x - a7.x, a3.y - a7.y);
            float2 O0 = make_float2(u0.x + u2.x, u0.y + u2.y);
            float2 O2 = make_float2(u0.x - u2.x, u0.y - u2.y);
            float2 O1 = make_float2(u1.x + u3.y, u1.y - u3.x);
            float2 O3 = make_float2(u1.x - u3.y, u1.y + u3.x);
            float2 r1 = make_float2(INVSQRT2 * (O1.x + O1.y), INVSQRT2 * (O1.y - O1.x));
            float2 r2 = make_float2(O2.y, -O2.x);
            float2 r3 = make_float2(INVSQRT2 * (O3.y - O3.x), -INVSQRT2 * (O3.x + O3.y));

            zb[PIDX(base)]         = make_float2(E0.x + O0.x, E0.y + O0.y);
            zb[PIDX(base + E)]     = make_float2(E1.x + r1.x, E1.y + r1.y);
            zb[PIDX(base + 2 * E)] = make_float2(E2.x + r2.x, E2.y + r2.y);
            zb[PIDX(base + 3 * E)] = make_float2(E3.x + r3.x, E3.y + r3.y);
            zb[PIDX(base + 4 * E)] = make_float2(E0.x - O0.x, E0.y - O0.y);
            zb[PIDX(base + 5 * E)] = make_float2(E1.x - r1.x, E1.y - r1.y);
            zb[PIDX(base + 6 * E)] = make_float2(E2.x - r2.x, E2.y - r2.y);
            zb[PIDX(base + 7 * E)] = make_float2(E3.x - r3.x, E3.y - r3.y);
        }
        __syncthreads();
    }

    for (int grp = tid; grp < 256; grp += NT) {
        int n0 = grp * 16;
#pragma unroll
        for (int half = 0; half < 2; half++) {
            unsigned short hi8[8];
#pragma unroll
            for (int e = 0; e < 8; e++) {
                int n = n0 + half * 8 + e;
                float win = 0.5f - 0.5f * cosf((TWO_PI / 4096.0f) * (float)n);
                hi8[e] = f2bf(win * zb[PIDX(n)].x);
            }
            int k  = ch * 4096 + n0 + half * 8;
            int ks = k >> 5;
            int l  = ((k >> 3) & 3) * 16 + j;
            uint4 ohi;
            ohi.x = (unsigned)hi8[0] | ((unsigned)hi8[1] << 16);
            ohi.y = (unsigned)hi8[2] | ((unsigned)hi8[3] << 16);
            ohi.z = (unsigned)hi8[4] | ((unsigned)hi8[5] << 16);
            ohi.w = (unsigned)hi8[6] | ((unsigned)hi8[7] << 16);
            *(uint4*)((char*)Bwf + (size_t)(ks * 5 + g) * 1024 + l * 16) = ohi;
        }
    }
    if (j == 0 && ch == 0) {
        for (int t = tid; t < NKS * 4; t += NT) {
            int ks = t >> 2;
            int qq = t & 3;
            *(uint4*)((char*)Bwf + (size_t)(ks * 5 + g) * 1024 + (qq * 16 + 15) * 16)
                = make_uint4(0u, 0u, 0u, 0u);
        }
    }
}

// Phase M: MFMA GEMM from pre-padded bf16 signal; 2-deep load pipeline
// (A loads issued 2 chunks ahead of use; B fragments likewise 2 groups ahead).
__device__ __forceinline__ void phaseM(int blk, int tid, unsigned int* AtileMem,
                                       const unsigned short* __restrict__ xbf,
                                       const unsigned int* __restrict__ Bwf,
                                       float* __restrict__ PC) {
    unsigned int (*Atile)[2048] = (unsigned int (*)[2048])AtileMem;
    int ksp = blk & 7;
    int mt  = (blk >> 3) % 9;
    int b   = blk / 72;
    int g   = tid >> 6;
    int l   = tid & 63;
    int lm  = l & 15;
    int q   = l >> 4;

    int ch = ksp >> 2;
    int n0 = (ksp & 3) * 1024;

    int srow = tid >> 3;
    int skq  = tid & 7;
    const unsigned short* xr = xbf + (size_t)(b * 2 + ch) * XPADL
                             + (size_t)(mt * 32 + srow) * 1024 + n0 + skq * 8;

    f32x4 acc0 = {0.f, 0.f, 0.f, 0.f};
    f32x4 acc1 = {0.f, 0.f, 0.f, 0.f};

    // Two pending A-load sets: pA = destined for chunk (write next), pB = one later.
    uint4 pA0, pA1, pB0, pB1;
    auto issueA = [&](int cc, uint4& d0, uint4& d1) {
        d0 = *(const uint4*)(xr + cc * 128);
        d1 = *(const uint4*)(xr + cc * 128 + 64);
    };
    auto writebuf = [&](int buf, const uint4& d0, const uint4& d1) {
        int key = (srow & 7) << 4;
        int w0 = srow * 256 + ((skq * 16) ^ key);
        int w1 = srow * 256 + (((128 + skq * 16)) ^ key);   // bit7 untouched by key
        *(uint4*)((char*)Atile[buf] + w0) = d0;
        *(uint4*)((char*)Atile[buf] + w1) = d1;
    };

    const char* bbase = (const char*)Bwf + (size_t)g * 1024 + l * 16;
    int ks0 = ksp * 32;

    // B double-prefetch state: bc = current chunk's 4 records, bn = next chunk's.
    bf16x8 bc0, bc1, bc2, bc3, bn0, bn1, bn2, bn3;
    auto loadB = [&](int cc, bf16x8& r0, bf16x8& r1, bf16x8& r2, bf16x8& r3) {
        int ks = ks0 + cc * 4;
        r0 = *(const bf16x8*)(bbase + (size_t)(ks + 0) * 5120);
        r1 = *(const bf16x8*)(bbase + (size_t)(ks + 1) * 5120);
        r2 = *(const bf16x8*)(bbase + (size_t)(ks + 2) * 5120);
        r3 = *(const bf16x8*)(bbase + (size_t)(ks + 3) * 5120);
    };

    // prologue: stage chunk 0; issue loads for chunks 1 and 2 (2-deep)
    if (tid < 256) {
        issueA(0, pA0, pA1);
        writebuf(0, pA0, pA1);
        issueA(1, pA0, pA1);      // pending for chunk 1
        issueA(2, pB0, pB1);      // pending for chunk 2
    }
    loadB(0, bc0, bc1, bc2, bc3);
    loadB(1, bn0, bn1, bn2, bn3);
    __syncthreads();

#pragma unroll
    for (int cc = 0; cc < CHPS; cc++) {
        const char* At = (const char*)Atile[cc & 1];
        auto kstep = [&](int kk, bf16x8 bh) {
            int off0 = lm * 256 + ((kk * 64 + q * 16) ^ ((lm & 7) << 4));
            bf16x8 a0 = *(const bf16x8*)(At + off0);
            bf16x8 a1 = *(const bf16x8*)(At + off0 + 4096);
            acc0 = __builtin_amdgcn_mfma_f32_16x16x32_bf16(a0, bh, acc0, 0, 0, 0);
            acc1 = __builtin_amdgcn_mfma_f32_16x16x32_bf16(a1, bh, acc1, 0, 0, 0);
        };
        kstep(0, bc0); kstep(1, bc1); kstep(2, bc2); kstep(3, bc3);

        if (cc + 1 < CHPS) {
            // rotate B: current <- next, prefetch next-next
            bc0 = bn0; bc1 = bn1; bc2 = bn2; bc3 = bn3;
            if (cc + 2 < CHPS) loadB(cc + 2, bn0, bn1, bn2, bn3);
            if (tid < 256) {
                writebuf((cc + 1) & 1, pA0, pA1);   // issued 2 chunks ago
                pA0 = pB0; pA1 = pB1;
                if (cc + 3 < CHPS) issueA(cc + 3, pB0, pB1);
            }
            __syncthreads();
        }
    }

    float* pc = PC + (((size_t)(ksp * 8 + b) * FPADR + mt * 32) * NCOL) + g * 16 + lm;
#pragma unroll
    for (int r = 0; r < 4; r++) {
        pc[(q * 4 + r) * NCOL] = acc0[r];
        pc[(16 + q * 4 + r) * NCOL] = acc1[r];
    }
}

// Phase K: one wave per (b,f): combine K-splits + ctx fold + MLP2/3 -> mask
__device__ __forceinline__ void phaseK(int wv, int l,
                                       const float* __restrict__ PC,
                                       const float* __restrict__ b1,
                                       const float* __restrict__ w2,
                                       const float* __restrict__ b2,
                                       const float* __restrict__ w3,
                                       const float* __restrict__ b3,
                                       float* __restrict__ mask) {
    if (wv >= BATCH * NFRM) return;
    int b = wv / NFRM;
    int f = wv - b * NFRM;

    float4 v0 = make_float4(0.f, 0.f, 0.f, 0.f), v1 = v0, v2 = v0, v3 = v0;
    if (l < KSPL * 5) {
        int ksp = l / 5;
        int g   = l - ksp * 5;
        int fr  = f - 2 + g;
        if (fr >= 0 && fr < NFRM) {
            const float4* p = (const float4*)(PC + (((size_t)(ksp * 8 + b) * FPADR + fr) * NCOL) + g * 16);
            v0 = p[0]; v1 = p[1]; v2 = p[2]; v3 = p[3];
        }
    }
#pragma unroll
    for (int off = 32; off > 0; off >>= 1) {
        v0.x += __shfl_xor(v0.x, off); v0.y += __shfl_xor(v0.y, off);
        v0.z += __shfl_xor(v0.z, off); v0.w += __shfl_xor(v0.w, off);
        v1.x += __shfl_xor(v1.x, off); v1.y += __shfl_xor(v1.y, off);
        v1.z += __shfl_xor(v1.z, off); v1.w += __shfl_xor(v1.w, off);
        v2.x += __shfl_xor(v2.x, off); v2.y += __shfl_xor(v2.y, off);
        v2.z += __shfl_xor(v2.z, off); v2.w += __shfl_xor(v2.w, off);
        v3.x += __shfl_xor(v3.x, off); v3.y += __shfl_xor(v3.y, off);
        v3.z += __shfl_xor(v3.z, off); v3.w += __shfl_xor(v3.w, off);
    }
    if (l == 0) {
        float h[16];
        *(float4*)&h[0]  = v0; *(float4*)&h[4]  = v1;
        *(float4*)&h[8]  = v2; *(float4*)&h[12] = v3;
#pragma unroll
        for (int jj = 0; jj < 15; jj++) {
            float vv = h[jj] + b1[jj];
            h[jj] = vv > 0.f ? vv : 0.f;
        }
        float hh[10];
#pragma unroll
        for (int k = 0; k < 10; k++) {
            float s = b2[k];
#pragma unroll
            for (int jj = 0; jj < 15; jj++) s += h[jj] * w2[jj * 10 + k];
            hh[k] = s > 0.f ? s : 0.f;
        }
        float vv = b3[0];
#pragma unroll
        for (int k = 0; k < 10; k++) vv += hh[k] * w3[k];
        mask[wv] = 1.f / (1.f + expf(-vv));
    }
}

// Phase O: per-sample analytic masked ISTFT
__device__ __forceinline__ void phaseO(int idx, const float* __restrict__ x,
                                       const float* __restrict__ mask,
                                       float* __restrict__ out) {
    int t  = idx & (TLEN - 1);
    int bc = idx >> 18;
    int b  = bc >> 1;
    int tau = t + PAD;
    int T = tau >> 10;
    int u = tau & 1023;
    float sv, cv;
    sincosf((TWO_PI / 4096.0f) * (float)u, &sv, &cv);
    float c4[4] = {cv, -sv, -cv, sv};
    float s0 = 0.f, s1 = 0.f;
    const float* mb = mask + b * NFRM;
#pragma unroll
    for (int i = 0; i < 4; i++) {
        int f = T - i;
        if (f >= 0 && f < NFRM) {
            float w = 0.5f - 0.5f * c4[i];
            float w2v = w * w;
            s0 += w2v;
            s1 += mb[f] * w2v;
        }
    }
    float denom = (s0 > 1e-11f) ? s0 : 1.0f;
    out[idx] = x[idx] * (s1 / denom);
}

// =================== software grid barrier (persistent blocks) ======================
__device__ __forceinline__ void gbar(unsigned* bar, unsigned round) {
    __threadfence();                 // device-scope: prior writes visible
    __syncthreads();
    if (threadIdx.x == 0) {
        __hip_atomic_fetch_add(bar, 1u, __ATOMIC_ACQ_REL, __HIP_MEMORY_SCOPE_AGENT);
        unsigned target = round * GRID;
        while (__hip_atomic_load(bar, __ATOMIC_ACQUIRE, __HIP_MEMORY_SCOPE_AGENT) < target) {
            __builtin_amdgcn_s_sleep(8);
        }
    }
    __syncthreads();
}

// =================== mega kernel (persistent grid, 3 barriers) ======================
__global__ __launch_bounds__(NTHR, 4) void mega_kernel(const float* __restrict__ x,
                                                       const float* __restrict__ w1,
                                                       const float* __restrict__ b1,
                                                       const float* __restrict__ w2,
                                                       const float* __restrict__ b2,
                                                       const float* __restrict__ w3,
                                                       const float* __restrict__ b3,
                                                       unsigned int* __restrict__ Bwf,
                                                       unsigned short* __restrict__ xbf,
                                                       float* __restrict__ PC,
                                                       float* __restrict__ mask,
                                                       float* __restrict__ out,
                                                       unsigned* __restrict__ bar) {
    __shared__ __align__(16) float2 smem[4368];   // 34.9 KB; zb in D, Atile in M
    int blk = blockIdx.x;
    int tid = threadIdx.x;

    // Phase D on blocks 0..149; idle blocks 150..575 materialize bf16 padded x.
    if (blk < 150) phaseD<NTHR>(blk, tid, smem, w1, Bwf);
    else           phaseX((blk - 150) * NTHR + tid, (GRID - 150) * NTHR, x, xbf);
    gbar(bar, 1);

    phaseM(blk, tid, (unsigned int*)smem, xbf, Bwf, PC);
    gbar(bar, 2);

    phaseK(blk * 5 + (tid >> 6), tid & 63, PC, b1, w2, b2, w3, b3, mask);
    gbar(bar, 3);

    for (int idx = blk * NTHR + tid; idx < BATCH * 2 * TLEN; idx += GRID * NTHR)
        phaseO(idx, x, mask, out);
}

// =================== fallback kernels (5-kernel chain, same math) ===================
__global__ __launch_bounds__(256) void xprep_kernel(const float* __restrict__ x,
                                                    unsigned short* __restrict__ xbf) {
    phaseX(blockIdx.x * 256 + threadIdx.x, gridDim.x * 256, x, xbf);
}
__global__ __launch_bounds__(256) void dfft_fused_kernel(const float* __restrict__ w1,
                                                         unsigned int* __restrict__ Bwf) {
    __shared__ __align__(16) float2 zb[4368];
    phaseD<256>(blockIdx.x, threadIdx.x, zb, w1, Bwf);
}
__global__ __launch_bounds__(320) void mlp_mfma_kernel(const unsigned short* __restrict__ xbf,
                                                       const unsigned int* __restrict__ Bwf,
                                                       float* __restrict__ PC) {
    __shared__ __align__(16) unsigned int Atile[2][2048];
    phaseM(blockIdx.x, threadIdx.x, &Atile[0][0], xbf, Bwf, PC);
}
__global__ __launch_bounds__(256) void mask_kernel(const float* __restrict__ PC,
                                                   const float* __restrict__ b1,
                                                   const float* __restrict__ w2,
                                                   const float* __restrict__ b2,
                                                   const float* __restrict__ w3,
                                                   const float* __restrict__ b3,
                                                   float* __restrict__ mask) {
    phaseK(blockIdx.x * 4 + (threadIdx.x >> 6), threadIdx.x & 63,
           PC, b1, w2, b2, w3, b3, mask);
}
__global__ __launch_bounds__(256) void ola_kernel(const float* __restrict__ x,
                                                  const float* __restrict__ mask,
                                                  float* __restrict__ out) {
    phaseO(blockIdx.x * 256 + threadIdx.x, x, mask, out);
}

// ---------------- launch ----------------
extern "C" void kernel_launch(void* const* d_in, const int* in_sizes, int n_in,
                              void* d_out, int out_size, void* d_ws, size_t ws_size,
                              hipStream_t stream) {
    const float* x  = (const float*)d_in[0];
    const float* w1 = (const float*)d_in[1];
    const float* b1 = (const float*)d_in[2];
    const float* w2 = (const float*)d_in[3];
    const float* b2 = (const float*)d_in[4];
    const float* w3 = (const float*)d_in[5];
    const float* b3 = (const float*)d_in[6];

    char* wsp = (char*)d_ws;
    size_t off = 0;
    auto alloc = [&](size_t bytes) { void* p = wsp + off; off = (off + bytes + 511) & ~(size_t)511; return p; };

    unsigned int* Bwf    = (unsigned int*)alloc((size_t)NKS * 5 * 1024);           // 1.31 MB
    unsigned short* xbf  = (unsigned short*)alloc((size_t)16 * XPADL * 2);         // 9.57 MB
    float* PC            = (float*)alloc((size_t)KSPL * 8 * FPADR * NCOL * 4);     // 5.90 MB
    float* mask          = (float*)alloc((size_t)BATCH * NFRM * 4);
    unsigned* bar        = (unsigned*)alloc(512);
    float* out = (float*)d_out;

    // persistent-grid feasibility: need GRID blocks co-resident (deadlock-free guard)
    int maxB = 0, dev = 0, numCU = 0;
    hipGetDevice(&dev);
    hipDeviceGetAttribute(&numCU, hipDeviceAttributeMultiprocessorCount, dev);
    hipError_t qerr = hipOccupancyMaxActiveBlocksPerMultiprocessor(&maxB, mega_kernel, NTHR, 0);

    if (qerr == hipSuccess && numCU > 0 && (size_t)maxB * (size_t)numCU >= GRID) {
        hipMemsetAsync(bar, 0, 64, stream);
        mega_kernel<<<GRID, NTHR, 0, stream>>>(x, w1, b1, w2, b2, w3, b3,
                                               Bwf, xbf, PC, mask, out, bar);
    } else {
        xprep_kernel<<<(16 * (XPADL / 8) + 255) / 256, 256, 0, stream>>>(x, xbf);
        dfft_fused_kernel<<<150, 256, 0, stream>>>(w1, Bwf);
        mlp_mfma_kernel<<<BATCH * 9 * KSPL, 320, 0, stream>>>(xbf, Bwf, PC);
        mask_kernel<<<(BATCH * NFRM + 3) / 4, 256, 0, stream>>>(PC, b1, w2, b2, w3, b3, mask);
        ola_kernel<<<(BATCH * 2 * TLEN) / 256, 256, 0, stream>>>(x, mask, out);
    }
}

// Round 22
// 56.352 us; speedup vs baseline: 1.0942x; 1.0942x over previous
//
#include <hip/hip_runtime.h>
#include <math.h>

#define NFRM  257
#define BATCH 8
#define TLEN  262144          // 2^18
#define PAD   2048
#define TWO_PI 6.2831853071795864769f
#define INVSQRT2 0.70710678118654752440f

#define FPADR 288             // padded frames: 9 m-tiles of 32
#define XPADL 299008          // bf16 padded signal length per (b,ch): 288*1024+4096
#define XVALID 266240         // TLEN + 2*PAD (valid xpad indices)
#define NKS   256             // k-steps of 32
#define KSPL  8               // K splits (each 8 chunks of 128 k = 1024 k)
#define CHPS  8               // chunks per K-split
#define NCOL  80              // 5 ctx groups x 16 (j padded 15->16)
#define GRID  576             // = BATCH * 9 * KSPL
#define NTHR  320

// padded LDS index (float2 units): breaks all 8^s stride bank conflicts
#define PIDX(i) ((i) + ((i) >> 4) + ((i) >> 8))

typedef short bf16x8 __attribute__((ext_vector_type(8)));
typedef float f32x4  __attribute__((ext_vector_type(4)));

__device__ __forceinline__ int reflect_idx(int s) {
    if (s < 0) s = -s;
    if (s >= TLEN) s = 2 * (TLEN - 1) - s;
    return s;
}
__device__ __forceinline__ unsigned short f2bf(float f) {
    unsigned int u = __float_as_uint(f);
    unsigned int r = (u + 0x7FFFu + ((u >> 16) & 1u)) >> 16;   // RTNE
    return (unsigned short)r;
}
__device__ __forceinline__ float2 cmul(float2 a, float2 b) {
    return make_float2(a.x * b.x - a.y * b.y, a.x * b.y + a.y * b.x);
}

// =================== shared phase bodies (used by mega AND fallback) ================

// Phase X: reflect-padded bf16 signal (runs on idle blocks during phase D)
__device__ __forceinline__ void phaseX(int gtid, int gstride,
                                       const float* __restrict__ x,
                                       unsigned short* __restrict__ xbf) {
    const int SPB = XPADL / 8;          // uint4-stores per (b,ch) = 37376
    const int NST = 16 * SPB;           // 598016
    for (int s = gtid; s < NST; s += gstride) {
        int bc = s / SPB;
        int i0 = (s - bc * SPB) * 8;
        const float* sig = x + (size_t)bc * TLEN;
        unsigned short v[8];
#pragma unroll
        for (int e = 0; e < 8; e++) {
            int i = i0 + e;
            float val = 0.f;
            if (i < XVALID) val = sig[reflect_idx(i - PAD)];
            v[e] = f2bf(val);
        }
        uint4 o;
        o.x = (unsigned)v[0] | ((unsigned)v[1] << 16);
        o.y = (unsigned)v[2] | ((unsigned)v[3] << 16);
        o.z = (unsigned)v[4] | ((unsigned)v[5] << 16);
        o.w = (unsigned)v[6] | ((unsigned)v[7] << 16);
        *(uint4*)(xbf + (size_t)bc * XPADL + i0) = o;
    }
}

// Phase D: w1 row (j,g,ch) -> 4096-pt FFT -> windowed FIR taps -> Bwf bf16 records
template<int NT>
__device__ __forceinline__ void phaseD(int blk, int tid, float2* zb,
                                       const float* __restrict__ w1,
                                       unsigned int* __restrict__ Bwf) {
    int ch = blk & 1;
    int jg = blk >> 1;
    int g  = jg % 5;
    int j  = jg / 5;
    int cA = ch, cB = ch + 2;

    for (int bin = tid; bin < 4096; bin += NT) {
        float ar = 0.f, ai = 0.f;
        if (bin <= 2048) {
            ar =  w1[(size_t)(bin * 20 + g * 4 + cA) * 15 + j];
            ai = -w1[(size_t)(bin * 20 + g * 4 + cB) * 15 + j];
        }
        int rev = ((bin & 7) << 9) | (((bin >> 3) & 7) << 6) | (((bin >> 6) & 7) << 3) | ((bin >> 9) & 7);
        zb[PIDX(rev)] = make_float2(ar, ai);
    }
    __syncthreads();

#pragma unroll
    for (int s = 0; s < 4; s++) {
        int E    = 1 << (3 * s);
        int step = 1 << (9 - 3 * s);
        for (int t = tid; t < 512; t += NT) {
            int pos = t & (E - 1);
            int bq  = t >> (3 * s);
            int base = (bq << (3 * s + 3)) + pos;

            float2 a0 = zb[PIDX(base)];
            float2 a1 = zb[PIDX(base + E)];
            float2 a2 = zb[PIDX(base + 2 * E)];
            float2 a3 = zb[PIDX(base + 3 * E)];
            float2 a4 = zb[PIDX(base + 4 * E)];
            float2 a5 = zb[PIDX(base + 5 * E)];
            float2 a6 = zb[PIDX(base + 6 * E)];
            float2 a7 = zb[PIDX(base + 7 * E)];

            if (s > 0) {
                float sv, cv;
                sincosf(-(TWO_PI * (float)(pos * step)) / 4096.0f, &sv, &cv);
                float2 w1t = make_float2(cv, sv);
                float2 w2t = cmul(w1t, w1t);
                float2 w3t = cmul(w2t, w1t);
                float2 w4t = cmul(w2t, w2t);
                float2 w5t = cmul(w3t, w2t);
                float2 w6t = cmul(w3t, w3t);
                float2 w7t = cmul(w4t, w3t);
                a1 = cmul(a1, w1t); a2 = cmul(a2, w2t); a3 = cmul(a3, w3t);
                a4 = cmul(a4, w4t); a5 = cmul(a5, w5t); a6 = cmul(a6, w6t);
                a7 = cmul(a7, w7t);
            }

            float2 t0 = make_float2(a0.x + a4.x, a0.y + a4.y);
            float2 t1 = make_float2(a0.x - a4.x, a0.y - a4.y);
            float2 t2 = make_float2(a2.x + a6.x, a2.y + a6.y);
            float2 t3 = make_float2(a2.x - a6.x, a2.y - a6.y);
            float2 E0 = make_float2(t0.x + t2.x, t0.y + t2.y);
            float2 E2 = make_float2(t0.x - t2.x, t0.y - t2.y);
            float2 E1 = make_float2(t1.x + t3.y, t1.y - t3.x);
            float2 E3 = make_float2(t1.x - t3.y, t1.y + t3.x);
            float2 u0 = make_float2(a1.x + a5.x, a1.y + a5.y);
            float2 u1 = make_float2(a1.x - a5.x, a1.y - a5.y);
            float2 u2 = make_float2(a3.x + a7.x, a3.y + a7.y);
            float2 u3 = make_float2(a3.x - a7.x, a3.y - a7.y);
            float2 O0 = make_float2(u0.x + u2.x, u0.y + u2.y);
            float2 O2 = make_float2(u0.x - u2.x, u0.y - u2.y);
            float2 O1 = make_float2(u1.x + u3.y, u1.y - u3.x);
            float2 O3 = make_float2(u1.x - u3.y, u1.y + u3.x);
            float2 r1 = make_float2(INVSQRT2 * (O1.x + O1.y), INVSQRT2 * (O1.y - O1.x));
            float2 r2 = make_float2(O2.y, -O2.x);
            float2 r3 = make_float2(INVSQRT2 * (O3.y - O3.x), -INVSQRT2 * (O3.x + O3.y));

            zb[PIDX(base)]         = make_float2(E0.x + O0.x, E0.y + O0.y);
            zb[PIDX(base + E)]     = make_float2(E1.x + r1.x, E1.y + r1.y);
            zb[PIDX(base + 2 * E)] = make_float2(E2.x + r2.x, E2.y + r2.y);
            zb[PIDX(base + 3 * E)] = make_float2(E3.x + r3.x, E3.y + r3.y);
            zb[PIDX(base + 4 * E)] = make_float2(E0.x - O0.x, E0.y - O0.y);
            zb[PIDX(base + 5 * E)] = make_float2(E1.x - r1.x, E1.y - r1.y);
            zb[PIDX(base + 6 * E)] = make_float2(E2.x - r2.x, E2.y - r2.y);
            zb[PIDX(base + 7 * E)] = make_float2(E3.x - r3.x, E3.y - r3.y);
        }
        __syncthreads();
    }

    for (int grp = tid; grp < 256; grp += NT) {
        int n0 = grp * 16;
#pragma unroll
        for (int half = 0; half < 2; half++) {
            unsigned short hi8[8];
#pragma unroll
            for (int e = 0; e < 8; e++) {
                int n = n0 + half * 8 + e;
                float win = 0.5f - 0.5f * cosf((TWO_PI / 4096.0f) * (float)n);
                hi8[e] = f2bf(win * zb[PIDX(n)].x);
            }
            int k  = ch * 4096 + n0 + half * 8;
            int ks = k >> 5;
            int l  = ((k >> 3) & 3) * 16 + j;
            uint4 ohi;
            ohi.x = (unsigned)hi8[0] | ((unsigned)hi8[1] << 16);
            ohi.y = (unsigned)hi8[2] | ((unsigned)hi8[3] << 16);
            ohi.z = (unsigned)hi8[4] | ((unsigned)hi8[5] << 16);
            ohi.w = (unsigned)hi8[6] | ((unsigned)hi8[7] << 16);
            *(uint4*)((char*)Bwf + (size_t)(ks * 5 + g) * 1024 + l * 16) = ohi;
        }
    }
    if (j == 0 && ch == 0) {
        for (int t = tid; t < NKS * 4; t += NT) {
            int ks = t >> 2;
            int qq = t & 3;
            *(uint4*)((char*)Bwf + (size_t)(ks * 5 + g) * 1024 + (qq * 16 + 15) * 16)
                = make_uint4(0u, 0u, 0u, 0u);
        }
    }
}

// Phase M: MFMA GEMM from pre-padded bf16 signal; 2-deep load pipeline.
__device__ __forceinline__ void phaseM(int blk, int tid, unsigned int* AtileMem,
                                       const unsigned short* __restrict__ xbf,
                                       const unsigned int* __restrict__ Bwf,
                                       float* __restrict__ PC) {
    unsigned int (*Atile)[2048] = (unsigned int (*)[2048])AtileMem;
    int ksp = blk & 7;
    int mt  = (blk >> 3) % 9;
    int b   = blk / 72;
    int g   = tid >> 6;
    int l   = tid & 63;
    int lm  = l & 15;
    int q   = l >> 4;

    int ch = ksp >> 2;
    int n0 = (ksp & 3) * 1024;

    int srow = tid >> 3;
    int skq  = tid & 7;
    const unsigned short* xr = xbf + (size_t)(b * 2 + ch) * XPADL
                             + (size_t)(mt * 32 + srow) * 1024 + n0 + skq * 8;

    f32x4 acc0 = {0.f, 0.f, 0.f, 0.f};
    f32x4 acc1 = {0.f, 0.f, 0.f, 0.f};

    uint4 pA0, pA1, pB0, pB1;
    auto issueA = [&](int cc, uint4& d0, uint4& d1) {
        d0 = *(const uint4*)(xr + cc * 128);
        d1 = *(const uint4*)(xr + cc * 128 + 64);
    };
    auto writebuf = [&](int buf, const uint4& d0, const uint4& d1) {
        int key = (srow & 7) << 4;
        int w0 = srow * 256 + ((skq * 16) ^ key);
        int w1 = srow * 256 + (((128 + skq * 16)) ^ key);   // bit7 untouched by key
        *(uint4*)((char*)Atile[buf] + w0) = d0;
        *(uint4*)((char*)Atile[buf] + w1) = d1;
    };

    const char* bbase = (const char*)Bwf + (size_t)g * 1024 + l * 16;
    int ks0 = ksp * 32;

    bf16x8 bc0, bc1, bc2, bc3, bn0, bn1, bn2, bn3;
    auto loadB = [&](int cc, bf16x8& r0, bf16x8& r1, bf16x8& r2, bf16x8& r3) {
        int ks = ks0 + cc * 4;
        r0 = *(const bf16x8*)(bbase + (size_t)(ks + 0) * 5120);
        r1 = *(const bf16x8*)(bbase + (size_t)(ks + 1) * 5120);
        r2 = *(const bf16x8*)(bbase + (size_t)(ks + 2) * 5120);
        r3 = *(const bf16x8*)(bbase + (size_t)(ks + 3) * 5120);
    };

    if (tid < 256) {
        issueA(0, pA0, pA1);
        writebuf(0, pA0, pA1);
        issueA(1, pA0, pA1);
        issueA(2, pB0, pB1);
    }
    loadB(0, bc0, bc1, bc2, bc3);
    loadB(1, bn0, bn1, bn2, bn3);
    __syncthreads();

#pragma unroll
    for (int cc = 0; cc < CHPS; cc++) {
        const char* At = (const char*)Atile[cc & 1];
        auto kstep = [&](int kk, bf16x8 bh) {
            int off0 = lm * 256 + ((kk * 64 + q * 16) ^ ((lm & 7) << 4));
            bf16x8 a0 = *(const bf16x8*)(At + off0);
            bf16x8 a1 = *(const bf16x8*)(At + off0 + 4096);
            acc0 = __builtin_amdgcn_mfma_f32_16x16x32_bf16(a0, bh, acc0, 0, 0, 0);
            acc1 = __builtin_amdgcn_mfma_f32_16x16x32_bf16(a1, bh, acc1, 0, 0, 0);
        };
        kstep(0, bc0); kstep(1, bc1); kstep(2, bc2); kstep(3, bc3);

        if (cc + 1 < CHPS) {
            bc0 = bn0; bc1 = bn1; bc2 = bn2; bc3 = bn3;
            if (cc + 2 < CHPS) loadB(cc + 2, bn0, bn1, bn2, bn3);
            if (tid < 256) {
                writebuf((cc + 1) & 1, pA0, pA1);
                pA0 = pB0; pA1 = pB1;
                if (cc + 3 < CHPS) issueA(cc + 3, pB0, pB1);
            }
            __syncthreads();
        }
    }

    float* pc = PC + (((size_t)(ksp * 8 + b) * FPADR + mt * 32) * NCOL) + g * 16 + lm;
#pragma unroll
    for (int r = 0; r < 4; r++) {
        pc[(q * 4 + r) * NCOL] = acc0[r];
        pc[(16 + q * 4 + r) * NCOL] = acc1[r];
    }
}

// Phase K: one wave per (b,f): combine K-splits + ctx fold + MLP2/3 -> mask
__device__ __forceinline__ void phaseK(int wv, int l,
                                       const float* __restrict__ PC,
                                       const float* __restrict__ b1,
                                       const float* __restrict__ w2,
                                       const float* __restrict__ b2,
                                       const float* __restrict__ w3,
                                       const float* __restrict__ b3,
                                       float* __restrict__ mask) {
    if (wv >= BATCH * NFRM) return;
    int b = wv / NFRM;
    int f = wv - b * NFRM;

    float4 v0 = make_float4(0.f, 0.f, 0.f, 0.f), v1 = v0, v2 = v0, v3 = v0;
    if (l < KSPL * 5) {
        int ksp = l / 5;
        int g   = l - ksp * 5;
        int fr  = f - 2 + g;
        if (fr >= 0 && fr < NFRM) {
            const float4* p = (const float4*)(PC + (((size_t)(ksp * 8 + b) * FPADR + fr) * NCOL) + g * 16);
            v0 = p[0]; v1 = p[1]; v2 = p[2]; v3 = p[3];
        }
    }
#pragma unroll
    for (int off = 32; off > 0; off >>= 1) {
        v0.x += __shfl_xor(v0.x, off); v0.y += __shfl_xor(v0.y, off);
        v0.z += __shfl_xor(v0.z, off); v0.w += __shfl_xor(v0.w, off);
        v1.x += __shfl_xor(v1.x, off); v1.y += __shfl_xor(v1.y, off);
        v1.z += __shfl_xor(v1.z, off); v1.w += __shfl_xor(v1.w, off);
        v2.x += __shfl_xor(v2.x, off); v2.y += __shfl_xor(v2.y, off);
        v2.z += __shfl_xor(v2.z, off); v2.w += __shfl_xor(v2.w, off);
        v3.x += __shfl_xor(v3.x, off); v3.y += __shfl_xor(v3.y, off);
        v3.z += __shfl_xor(v3.z, off); v3.w += __shfl_xor(v3.w, off);
    }
    if (l == 0) {
        float h[16];
        *(float4*)&h[0]  = v0; *(float4*)&h[4]  = v1;
        *(float4*)&h[8]  = v2; *(float4*)&h[12] = v3;
#pragma unroll
        for (int jj = 0; jj < 15; jj++) {
            float vv = h[jj] + b1[jj];
            h[jj] = vv > 0.f ? vv : 0.f;
        }
        float hh[10];
#pragma unroll
        for (int k = 0; k < 10; k++) {
            float s = b2[k];
#pragma unroll
            for (int jj = 0; jj < 15; jj++) s += h[jj] * w2[jj * 10 + k];
            hh[k] = s > 0.f ? s : 0.f;
        }
        float vv = b3[0];
#pragma unroll
        for (int k = 0; k < 10; k++) vv += hh[k] * w3[k];
        mask[wv] = 1.f / (1.f + expf(-vv));
    }
}

// Phase O prep: wsq[u][i] = window(u + 1024*i)^2 for u in [0,1024) -> LDS (16 KB)
template<int NT>
__device__ __forceinline__ void buildWsq(int tid, float4* wsq) {
    for (int u = tid; u < 1024; u += NT) {
        float sv, cv;
        sincosf((TWO_PI / 4096.0f) * (float)u, &sv, &cv);
        float c4[4] = {cv, -sv, -cv, sv};
        float4 w;
        float w0 = 0.5f - 0.5f * c4[0]; w.x = w0 * w0;
        float w1 = 0.5f - 0.5f * c4[1]; w.y = w1 * w1;
        float w2 = 0.5f - 0.5f * c4[2]; w.z = w2 * w2;
        float w3 = 0.5f - 0.5f * c4[3]; w.w = w3 * w3;
        wsq[u] = w;
    }
    __syncthreads();
}

// Phase O: vectorized masked OLA — 4 samples/iter, trig from LDS table.
// 4-aligned groups never straddle a 1024-run, so T and validity are uniform.
__device__ __forceinline__ void phaseO(int gtid, int gstride,
                                       const float4* __restrict__ wsq,
                                       const float* __restrict__ x,
                                       const float* __restrict__ mask,
                                       float* __restrict__ out) {
    const int NG = (BATCH * 2 * TLEN) / 4;   // 1048576 float4 groups
    for (int gidx = gtid; gidx < NG; gidx += gstride) {
        int idx = gidx * 4;
        int t  = idx & (TLEN - 1);
        int bc = idx >> 18;
        int b  = bc >> 1;
        int tau = t + PAD;
        int T = tau >> 10;
        int u0 = tau & 1023;
        const float* mb = mask + b * NFRM;

        float mv[4];
        bool vd[4];
#pragma unroll
        for (int i = 0; i < 4; i++) {
            int f = T - i;
            vd[i] = (f >= 0) && (f < NFRM);
            mv[i] = vd[i] ? mb[f] : 0.f;
        }

        float4 xv = *(const float4*)(x + idx);
        float r[4];
#pragma unroll
        for (int jj = 0; jj < 4; jj++) {
            float4 w = wsq[u0 + jj];
            float ws[4] = {w.x, w.y, w.z, w.w};
            float s0 = 0.f, s1 = 0.f;
#pragma unroll
            for (int i = 0; i < 4; i++) {
                if (vd[i]) { s0 += ws[i]; s1 += mv[i] * ws[i]; }
            }
            float denom = (s0 > 1e-11f) ? s0 : 1.0f;
            r[jj] = s1 / denom;
        }
        float4 ov;
        ov.x = xv.x * r[0]; ov.y = xv.y * r[1];
        ov.z = xv.z * r[2]; ov.w = xv.w * r[3];
        *(float4*)(out + idx) = ov;
    }
}

// =================== software grid barrier (persistent blocks) ======================
__device__ __forceinline__ void gbar(unsigned* bar, unsigned round) {
    __threadfence();                 // device-scope: prior writes visible
    __syncthreads();
    if (threadIdx.x == 0) {
        __hip_atomic_fetch_add(bar, 1u, __ATOMIC_ACQ_REL, __HIP_MEMORY_SCOPE_AGENT);
        unsigned target = round * GRID;
        while (__hip_atomic_load(bar, __ATOMIC_ACQUIRE, __HIP_MEMORY_SCOPE_AGENT) < target) {
            __builtin_amdgcn_s_sleep(8);
        }
    }
    __syncthreads();
}

// =================== mega kernel (persistent grid, 3 barriers) ======================
__global__ __launch_bounds__(NTHR, 4) void mega_kernel(const float* __restrict__ x,
                                                       const float* __restrict__ w1,
                                                       const float* __restrict__ b1,
                                                       const float* __restrict__ w2,
                                                       const float* __restrict__ b2,
                                                       const float* __restrict__ w3,
                                                       const float* __restrict__ b3,
                                                       unsigned int* __restrict__ Bwf,
                                                       unsigned short* __restrict__ xbf,
                                                       float* __restrict__ PC,
                                                       float* __restrict__ mask,
                                                       float* __restrict__ out,
                                                       unsigned* __restrict__ bar) {
    __shared__ __align__(16) float2 smem[4368];   // 34.9 KB; zb in D, Atile in M, wsq in O
    int blk = blockIdx.x;
    int tid = threadIdx.x;

    // Phase D on blocks 0..149; idle blocks 150..575 materialize bf16 padded x.
    if (blk < 150) phaseD<NTHR>(blk, tid, smem, w1, Bwf);
    else           phaseX((blk - 150) * NTHR + tid, (GRID - 150) * NTHR, x, xbf);
    gbar(bar, 1);

    phaseM(blk, tid, (unsigned int*)smem, xbf, Bwf, PC);
    gbar(bar, 2);

    phaseK(blk * 5 + (tid >> 6), tid & 63, PC, b1, w2, b2, w3, b3, mask);
    gbar(bar, 3);

    buildWsq<NTHR>(tid, (float4*)smem);
    phaseO(blk * NTHR + tid, GRID * NTHR, (const float4*)smem, x, mask, out);
}

// =================== fallback kernels (5-kernel chain, same math) ===================
__global__ __launch_bounds__(256) void xprep_kernel(const float* __restrict__ x,
                                                    unsigned short* __restrict__ xbf) {
    phaseX(blockIdx.x * 256 + threadIdx.x, gridDim.x * 256, x, xbf);
}
__global__ __launch_bounds__(256) void dfft_fused_kernel(const float* __restrict__ w1,
                                                         unsigned int* __restrict__ Bwf) {
    __shared__ __align__(16) float2 zb[4368];
    phaseD<256>(blockIdx.x, threadIdx.x, zb, w1, Bwf);
}
__global__ __launch_bounds__(320) void mlp_mfma_kernel(const unsigned short* __restrict__ xbf,
                                                       const unsigned int* __restrict__ Bwf,
                                                       float* __restrict__ PC) {
    __shared__ __align__(16) unsigned int Atile[2][2048];
    phaseM(blockIdx.x, threadIdx.x, &Atile[0][0], xbf, Bwf, PC);
}
__global__ __launch_bounds__(256) void mask_kernel(const float* __restrict__ PC,
                                                   const float* __restrict__ b1,
                                                   const float* __restrict__ w2,
                                                   const float* __restrict__ b2,
                                                   const float* __restrict__ w3,
                                                   const float* __restrict__ b3,
                                                   float* __restrict__ mask) {
    phaseK(blockIdx.x * 4 + (threadIdx.x >> 6), threadIdx.x & 63,
           PC, b1, w2, b2, w3, b3, mask);
}
__global__ __launch_bounds__(256) void ola_kernel(const float* __restrict__ x,
                                                  const float* __restrict__ mask,
                                                  float* __restrict__ out) {
    __shared__ __align__(16) float4 wsq[1024];
    buildWsq<256>(threadIdx.x, wsq);
    phaseO(blockIdx.x * 256 + threadIdx.x, gridDim.x * 256, wsq, x, mask, out);
}

// ---------------- launch ----------------
extern "C" void kernel_launch(void* const* d_in, const int* in_sizes, int n_in,
                              void* d_out, int out_size, void* d_ws, size_t ws_size,
                              hipStream_t stream) {
    const float* x  = (const float*)d_in[0];
    const float* w1 = (const float*)d_in[1];
    const float* b1 = (const float*)d_in[2];
    const float* w2 = (const float*)d_in[3];
    const float* b2 = (const float*)d_in[4];
    const float* w3 = (const float*)d_in[5];
    const float* b3 = (const float*)d_in[6];

    char* wsp = (char*)d_ws;
    size_t off = 0;
    auto alloc = [&](size_t bytes) { void* p = wsp + off; off = (off + bytes + 511) & ~(size_t)511; return p; };

    unsigned int* Bwf    = (unsigned int*)alloc((size_t)NKS * 5 * 1024);           // 1.31 MB
    unsigned short* xbf  = (unsigned short*)alloc((size_t)16 * XPADL * 2);         // 9.57 MB
    float* PC            = (float*)alloc((size_t)KSPL * 8 * FPADR * NCOL * 4);     // 5.90 MB
    float* mask          = (float*)alloc((size_t)BATCH * NFRM * 4);
    unsigned* bar        = (unsigned*)alloc(512);
    float* out = (float*)d_out;

    // persistent-grid feasibility: need GRID blocks co-resident (deadlock-free guard)
    int maxB = 0, dev = 0, numCU = 0;
    hipGetDevice(&dev);
    hipDeviceGetAttribute(&numCU, hipDeviceAttributeMultiprocessorCount, dev);
    hipError_t qerr = hipOccupancyMaxActiveBlocksPerMultiprocessor(&maxB, mega_kernel, NTHR, 0);

    if (qerr == hipSuccess && numCU > 0 && (size_t)maxB * (size_t)numCU >= GRID) {
        hipMemsetAsync(bar, 0, 64, stream);
        mega_kernel<<<GRID, NTHR, 0, stream>>>(x, w1, b1, w2, b2, w3, b3,
                                               Bwf, xbf, PC, mask, out, bar);
    } else {
        xprep_kernel<<<(16 * (XPADL / 8) + 255) / 256, 256, 0, stream>>>(x, xbf);
        dfft_fused_kernel<<<150, 256, 0, stream>>>(w1, Bwf);
        mlp_mfma_kernel<<<BATCH * 9 * KSPL, 320, 0, stream>>>(xbf, Bwf, PC);
        mask_kernel<<<(BATCH * NFRM + 3) / 4, 256, 0, stream>>>(PC, b1, w2, b2, w3, b3, mask);
        ola_kernel<<<(BATCH * 2 * TLEN + 1023) / 1024, 256, 0, stream>>>(x, mask, out);
    }
}

// Round 23
// 56.179 us; speedup vs baseline: 1.0976x; 1.0031x over previous
//
#include <hip/hip_runtime.h>
#include <math.h>

#define NFRM  257
#define BATCH 8
#define TLEN  262144          // 2^18
#define PAD   2048
#define TWO_PI 6.2831853071795864769f
#define INVSQRT2 0.70710678118654752440f

#define FPADR 288             // padded frames: 9 m-tiles of 32
#define XPADL 299008          // bf16 padded signal length per (b,ch): 288*1024+4096
#define XVALID 266240         // TLEN + 2*PAD (valid xpad indices)
#define NKS   256             // k-steps of 32
#define KSPL  8               // K splits (each 8 chunks of 128 k = 1024 k)
#define CHPS  8               // chunks per K-split
#define NCOL  80              // 5 ctx groups x 16 (j padded 15->16)
#define GRID  576             // = BATCH * 9 * KSPL
#define NTHR  320

// padded LDS index (float2 units): breaks all 8^s stride bank conflicts
#define PIDX(i) ((i) + ((i) >> 4) + ((i) >> 8))

typedef short bf16x8 __attribute__((ext_vector_type(8)));
typedef float f32x4  __attribute__((ext_vector_type(4)));

__device__ __forceinline__ int reflect_idx(int s) {
    if (s < 0) s = -s;
    if (s >= TLEN) s = 2 * (TLEN - 1) - s;
    return s;
}
__device__ __forceinline__ unsigned short f2bf(float f) {
    unsigned int u = __float_as_uint(f);
    unsigned int r = (u + 0x7FFFu + ((u >> 16) & 1u)) >> 16;   // RTNE
    return (unsigned short)r;
}
__device__ __forceinline__ float2 cmul(float2 a, float2 b) {
    return make_float2(a.x * b.x - a.y * b.y, a.x * b.y + a.y * b.x);
}

// =================== shared phase bodies (used by mega AND fallback) ================

// Phase X: reflect-padded bf16 signal (runs on idle blocks during phase D)
__device__ __forceinline__ void phaseX(int gtid, int gstride,
                                       const float* __restrict__ x,
                                       unsigned short* __restrict__ xbf) {
    const int SPB = XPADL / 8;          // uint4-stores per (b,ch) = 37376
    const int NST = 16 * SPB;           // 598016
    for (int s = gtid; s < NST; s += gstride) {
        int bc = s / SPB;
        int i0 = (s - bc * SPB) * 8;
        const float* sig = x + (size_t)bc * TLEN;
        unsigned short v[8];
#pragma unroll
        for (int e = 0; e < 8; e++) {
            int i = i0 + e;
            float val = 0.f;
            if (i < XVALID) val = sig[reflect_idx(i - PAD)];
            v[e] = f2bf(val);
        }
        uint4 o;
        o.x = (unsigned)v[0] | ((unsigned)v[1] << 16);
        o.y = (unsigned)v[2] | ((unsigned)v[3] << 16);
        o.z = (unsigned)v[4] | ((unsigned)v[5] << 16);
        o.w = (unsigned)v[6] | ((unsigned)v[7] << 16);
        *(uint4*)(xbf + (size_t)bc * XPADL + i0) = o;
    }
}

// Phase D: w1 row (j,g,ch) -> 4096-pt FFT -> windowed FIR taps -> Bwf bf16 records
template<int NT>
__device__ __forceinline__ void phaseD(int blk, int tid, float2* zb,
                                       const float* __restrict__ w1,
                                       unsigned int* __restrict__ Bwf) {
    int ch = blk & 1;
    int jg = blk >> 1;
    int g  = jg % 5;
    int j  = jg / 5;
    int cA = ch, cB = ch + 2;

    for (int bin = tid; bin < 4096; bin += NT) {
        float ar = 0.f, ai = 0.f;
        if (bin <= 2048) {
            ar =  w1[(size_t)(bin * 20 + g * 4 + cA) * 15 + j];
            ai = -w1[(size_t)(bin * 20 + g * 4 + cB) * 15 + j];
        }
        int rev = ((bin & 7) << 9) | (((bin >> 3) & 7) << 6) | (((bin >> 6) & 7) << 3) | ((bin >> 9) & 7);
        zb[PIDX(rev)] = make_float2(ar, ai);
    }
    __syncthreads();

#pragma unroll
    for (int s = 0; s < 4; s++) {
        int E    = 1 << (3 * s);
        int step = 1 << (9 - 3 * s);
        for (int t = tid; t < 512; t += NT) {
            int pos = t & (E - 1);
            int bq  = t >> (3 * s);
            int base = (bq << (3 * s + 3)) + pos;

            float2 a0 = zb[PIDX(base)];
            float2 a1 = zb[PIDX(base + E)];
            float2 a2 = zb[PIDX(base + 2 * E)];
            float2 a3 = zb[PIDX(base + 3 * E)];
            float2 a4 = zb[PIDX(base + 4 * E)];
            float2 a5 = zb[PIDX(base + 5 * E)];
            float2 a6 = zb[PIDX(base + 6 * E)];
            float2 a7 = zb[PIDX(base + 7 * E)];

            if (s > 0) {
                float sv, cv;
                sincosf(-(TWO_PI * (float)(pos * step)) / 4096.0f, &sv, &cv);
                float2 w1t = make_float2(cv, sv);
                float2 w2t = cmul(w1t, w1t);
                float2 w3t = cmul(w2t, w1t);
                float2 w4t = cmul(w2t, w2t);
                float2 w5t = cmul(w3t, w2t);
                float2 w6t = cmul(w3t, w3t);
                float2 w7t = cmul(w4t, w3t);
                a1 = cmul(a1, w1t); a2 = cmul(a2, w2t); a3 = cmul(a3, w3t);
                a4 = cmul(a4, w4t); a5 = cmul(a5, w5t); a6 = cmul(a6, w6t);
                a7 = cmul(a7, w7t);
            }

            float2 t0 = make_float2(a0.x + a4.x, a0.y + a4.y);
            float2 t1 = make_float2(a0.x - a4.x, a0.y - a4.y);
            float2 t2 = make_float2(a2.x + a6.x, a2.y + a6.y);
            float2 t3 = make_float2(a2.x - a6.x, a2.y - a6.y);
            float2 E0 = make_float2(t0.x + t2.x, t0.y + t2.y);
            float2 E2 = make_float2(t0.x - t2.x, t0.y - t2.y);
            float2 E1 = make_float2(t1.x + t3.y, t1.y - t3.x);
            float2 E3 = make_float2(t1.x - t3.y, t1.y + t3.x);
            float2 u0 = make_float2(a1.x + a5.x, a1.y + a5.y);
            float2 u1 = make_float2(a1.x - a5.x, a1.y - a5.y);
            float2 u2 = make_float2(a3.x + a7.x, a3.y + a7.y);
            float2 u3 = make_float2(a3.x - a7.x, a3.y - a7.y);
            float2 O0 = make_float2(u0.x + u2.x, u0.y + u2.y);
            float2 O2 = make_float2(u0.x - u2.x, u0.y - u2.y);
            float2 O1 = make_float2(u1.x + u3.y, u1.y - u3.x);
            float2 O3 = make_float2(u1.x - u3.y, u1.y + u3.x);
            float2 r1 = make_float2(INVSQRT2 * (O1.x + O1.y), INVSQRT2 * (O1.y - O1.x));
            float2 r2 = make_float2(O2.y, -O2.x);
            float2 r3 = make_float2(INVSQRT2 * (O3.y - O3.x), -INVSQRT2 * (O3.x + O3.y));

            zb[PIDX(base)]         = make_float2(E0.x + O0.x, E0.y + O0.y);
            zb[PIDX(base + E)]     = make_float2(E1.x + r1.x, E1.y + r1.y);
            zb[PIDX(base + 2 * E)] = make_float2(E2.x + r2.x, E2.y + r2.y);
            zb[PIDX(base + 3 * E)] = make_float2(E3.x + r3.x, E3.y + r3.y);
            zb[PIDX(base + 4 * E)] = make_float2(E0.x - O0.x, E0.y - O0.y);
            zb[PIDX(base + 5 * E)] = make_float2(E1.x - r1.x, E1.y - r1.y);
            zb[PIDX(base + 6 * E)] = make_float2(E2.x - r2.x, E2.y - r2.y);
            zb[PIDX(base + 7 * E)] = make_float2(E3.x - r3.x, E3.y - r3.y);
        }
        __syncthreads();
    }

    for (int grp = tid; grp < 256; grp += NT) {
        int n0 = grp * 16;
#pragma unroll
        for (int half = 0; half < 2; half++) {
            unsigned short hi8[8];
#pragma unroll
            for (int e = 0; e < 8; e++) {
                int n = n0 + half * 8 + e;
                float win = 0.5f - 0.5f * cosf((TWO_PI / 4096.0f) * (float)n);
                hi8[e] = f2bf(win * zb[PIDX(n)].x);
            }
            int k  = ch * 4096 + n0 + half * 8;
            int ks = k >> 5;
            int l  = ((k >> 3) & 3) * 16 + j;
            uint4 ohi;
            ohi.x = (unsigned)hi8[0] | ((unsigned)hi8[1] << 16);
            ohi.y = (unsigned)hi8[2] | ((unsigned)hi8[3] << 16);
            ohi.z = (unsigned)hi8[4] | ((unsigned)hi8[5] << 16);
            ohi.w = (unsigned)hi8[6] | ((unsigned)hi8[7] << 16);
            *(uint4*)((char*)Bwf + (size_t)(ks * 5 + g) * 1024 + l * 16) = ohi;
        }
    }
    if (j == 0 && ch == 0) {
        for (int t = tid; t < NKS * 4; t += NT) {
            int ks = t >> 2;
            int qq = t & 3;
            *(uint4*)((char*)Bwf + (size_t)(ks * 5 + g) * 1024 + (qq * 16 + 15) * 16)
                = make_uint4(0u, 0u, 0u, 0u);
        }
    }
}

// Phase M: MFMA GEMM from pre-padded bf16 signal; 2-deep load pipeline.
__device__ __forceinline__ void phaseM(int blk, int tid, unsigned int* AtileMem,
                                       const unsigned short* __restrict__ xbf,
                                       const unsigned int* __restrict__ Bwf,
                                       float* __restrict__ PC) {
    unsigned int (*Atile)[2048] = (unsigned int (*)[2048])AtileMem;
    int ksp = blk & 7;
    int mt  = (blk >> 3) % 9;
    int b   = blk / 72;
    int g   = tid >> 6;
    int l   = tid & 63;
    int lm  = l & 15;
    int q   = l >> 4;

    int ch = ksp >> 2;
    int n0 = (ksp & 3) * 1024;

    int srow = tid >> 3;
    int skq  = tid & 7;
    const unsigned short* xr = xbf + (size_t)(b * 2 + ch) * XPADL
                             + (size_t)(mt * 32 + srow) * 1024 + n0 + skq * 8;

    f32x4 acc0 = {0.f, 0.f, 0.f, 0.f};
    f32x4 acc1 = {0.f, 0.f, 0.f, 0.f};

    uint4 pA0, pA1, pB0, pB1;
    auto issueA = [&](int cc, uint4& d0, uint4& d1) {
        d0 = *(const uint4*)(xr + cc * 128);
        d1 = *(const uint4*)(xr + cc * 128 + 64);
    };
    auto writebuf = [&](int buf, const uint4& d0, const uint4& d1) {
        int key = (srow & 7) << 4;
        int w0 = srow * 256 + ((skq * 16) ^ key);
        int w1 = srow * 256 + (((128 + skq * 16)) ^ key);   // bit7 untouched by key
        *(uint4*)((char*)Atile[buf] + w0) = d0;
        *(uint4*)((char*)Atile[buf] + w1) = d1;
    };

    const char* bbase = (const char*)Bwf + (size_t)g * 1024 + l * 16;
    int ks0 = ksp * 32;

    bf16x8 bc0, bc1, bc2, bc3, bn0, bn1, bn2, bn3;
    auto loadB = [&](int cc, bf16x8& r0, bf16x8& r1, bf16x8& r2, bf16x8& r3) {
        int ks = ks0 + cc * 4;
        r0 = *(const bf16x8*)(bbase + (size_t)(ks + 0) * 5120);
        r1 = *(const bf16x8*)(bbase + (size_t)(ks + 1) * 5120);
        r2 = *(const bf16x8*)(bbase + (size_t)(ks + 2) * 5120);
        r3 = *(const bf16x8*)(bbase + (size_t)(ks + 3) * 5120);
    };

    if (tid < 256) {
        issueA(0, pA0, pA1);
        writebuf(0, pA0, pA1);
        issueA(1, pA0, pA1);
        issueA(2, pB0, pB1);
    }
    loadB(0, bc0, bc1, bc2, bc3);
    loadB(1, bn0, bn1, bn2, bn3);
    __syncthreads();

#pragma unroll
    for (int cc = 0; cc < CHPS; cc++) {
        const char* At = (const char*)Atile[cc & 1];
        auto kstep = [&](int kk, bf16x8 bh) {
            int off0 = lm * 256 + ((kk * 64 + q * 16) ^ ((lm & 7) << 4));
            bf16x8 a0 = *(const bf16x8*)(At + off0);
            bf16x8 a1 = *(const bf16x8*)(At + off0 + 4096);
            acc0 = __builtin_amdgcn_mfma_f32_16x16x32_bf16(a0, bh, acc0, 0, 0, 0);
            acc1 = __builtin_amdgcn_mfma_f32_16x16x32_bf16(a1, bh, acc1, 0, 0, 0);
        };
        kstep(0, bc0); kstep(1, bc1); kstep(2, bc2); kstep(3, bc3);

        if (cc + 1 < CHPS) {
            bc0 = bn0; bc1 = bn1; bc2 = bn2; bc3 = bn3;
            if (cc + 2 < CHPS) loadB(cc + 2, bn0, bn1, bn2, bn3);
            if (tid < 256) {
                writebuf((cc + 1) & 1, pA0, pA1);
                pA0 = pB0; pA1 = pB1;
                if (cc + 3 < CHPS) issueA(cc + 3, pB0, pB1);
            }
            __syncthreads();
        }
    }

    float* pc = PC + (((size_t)(ksp * 8 + b) * FPADR + mt * 32) * NCOL) + g * 16 + lm;
#pragma unroll
    for (int r = 0; r < 4; r++) {
        pc[(q * 4 + r) * NCOL] = acc0[r];
        pc[(16 + q * 4 + r) * NCOL] = acc1[r];
    }
}

// Wave-level mask computation for one (b, f): returns mask in lane 0.
__device__ __forceinline__ float maskOf(int b, int f, int l,
                                        const float* __restrict__ PC,
                                        const float* __restrict__ b1,
                                        const float* __restrict__ w2,
                                        const float* __restrict__ b2,
                                        const float* __restrict__ w3,
                                        const float* __restrict__ b3) {
    float4 v0 = make_float4(0.f, 0.f, 0.f, 0.f), v1 = v0, v2 = v0, v3 = v0;
    if (l < KSPL * 5) {
        int ksp = l / 5;
        int g   = l - ksp * 5;
        int fr  = f - 2 + g;
        if (fr >= 0 && fr < NFRM) {
            const float4* p = (const float4*)(PC + (((size_t)(ksp * 8 + b) * FPADR + fr) * NCOL) + g * 16);
            v0 = p[0]; v1 = p[1]; v2 = p[2]; v3 = p[3];
        }
    }
#pragma unroll
    for (int off = 32; off > 0; off >>= 1) {
        v0.x += __shfl_xor(v0.x, off); v0.y += __shfl_xor(v0.y, off);
        v0.z += __shfl_xor(v0.z, off); v0.w += __shfl_xor(v0.w, off);
        v1.x += __shfl_xor(v1.x, off); v1.y += __shfl_xor(v1.y, off);
        v1.z += __shfl_xor(v1.z, off); v1.w += __shfl_xor(v1.w, off);
        v2.x += __shfl_xor(v2.x, off); v2.y += __shfl_xor(v2.y, off);
        v2.z += __shfl_xor(v2.z, off); v2.w += __shfl_xor(v2.w, off);
        v3.x += __shfl_xor(v3.x, off); v3.y += __shfl_xor(v3.y, off);
        v3.z += __shfl_xor(v3.z, off); v3.w += __shfl_xor(v3.w, off);
    }
    float res = 0.f;
    if (l == 0) {
        float h[16];
        *(float4*)&h[0]  = v0; *(float4*)&h[4]  = v1;
        *(float4*)&h[8]  = v2; *(float4*)&h[12] = v3;
#pragma unroll
        for (int jj = 0; jj < 15; jj++) {
            float vv = h[jj] + b1[jj];
            h[jj] = vv > 0.f ? vv : 0.f;
        }
        float hh[10];
#pragma unroll
        for (int k = 0; k < 10; k++) {
            float s = b2[k];
#pragma unroll
            for (int jj = 0; jj < 15; jj++) s += h[jj] * w2[jj * 10 + k];
            hh[k] = s > 0.f ? s : 0.f;
        }
        float vv = b3[0];
#pragma unroll
        for (int k = 0; k < 10; k++) vv += hh[k] * w3[k];
        res = 1.f / (1.f + expf(-vv));
    }
    return res;
}

// Phase K (fallback): one wave per (b,f) -> global mask
__device__ __forceinline__ void phaseK(int wv, int l,
                                       const float* __restrict__ PC,
                                       const float* __restrict__ b1,
                                       const float* __restrict__ w2,
                                       const float* __restrict__ b2,
                                       const float* __restrict__ w3,
                                       const float* __restrict__ b3,
                                       float* __restrict__ mask) {
    if (wv >= BATCH * NFRM) return;
    int b = wv / NFRM;
    int f = wv - b * NFRM;
    float m = maskOf(b, f, l, PC, b1, w2, b2, w3, b3);
    if (l == 0) mask[wv] = m;
}

// Phase O prep: wsq[u][i] = window(u + 1024*i)^2 for u in [0,1024) -> LDS (16 KB)
template<int NT>
__device__ __forceinline__ void buildWsq(int tid, float4* wsq) {
    for (int u = tid; u < 1024; u += NT) {
        float sv, cv;
        sincosf((TWO_PI / 4096.0f) * (float)u, &sv, &cv);
        float c4[4] = {cv, -sv, -cv, sv};
        float4 w;
        float w0 = 0.5f - 0.5f * c4[0]; w.x = w0 * w0;
        float w1 = 0.5f - 0.5f * c4[1]; w.y = w1 * w1;
        float w2 = 0.5f - 0.5f * c4[2]; w.z = w2 * w2;
        float w3 = 0.5f - 0.5f * c4[3]; w.w = w3 * w3;
        wsq[u] = w;
    }
}

// Fused K+O (mega): per-block in-LDS mask for its contiguous bc-range, then stream.
// Block blk: bc = blk/36, sub = blk%36; groups [sub*1821, ...) of TLEN/4 per bc.
__device__ __forceinline__ void phaseKO(int blk, int tid, float2* smem,
                                        const float* __restrict__ PC,
                                        const float* __restrict__ b1,
                                        const float* __restrict__ w2,
                                        const float* __restrict__ b2,
                                        const float* __restrict__ w3,
                                        const float* __restrict__ b3,
                                        const float* __restrict__ x,
                                        float* __restrict__ out) {
    float4* wsq   = (float4*)smem;                 // 16 KB
    float*  smask = (float*)((char*)smem + 16384); // 16 floats

    buildWsq<NTHR>(tid, wsq);

    const int GPB = TLEN / 4;          // 65536 groups per (b,ch)
    int bc  = blk / 36;                // 0..15
    int sub = blk - bc * 36;           // 0..35
    int gi0 = sub * 1821;
    int gi1 = gi0 + 1821; if (gi1 > GPB) gi1 = GPB;
    int b   = bc >> 1;

    int t0 = gi0 * 4, t1 = gi1 * 4 - 1;
    int Tlo = (t0 + PAD) >> 10;
    int Thi = (t1 + PAD) >> 10;
    int flo = Tlo - 3; if (flo < 0) flo = 0;
    int fhi = Thi; if (fhi > NFRM - 1) fhi = NFRM - 1;

    // 5 waves compute the <=13 needed mask values into LDS
    int w = tid >> 6, l = tid & 63;
    for (int f = flo + w; f <= fhi; f += 5) {
        float m = maskOf(b, f, l, PC, b1, w2, b2, w3, b3);
        if (l == 0) smask[f - flo] = m;
    }
    __syncthreads();

    const float* xc = x   + (size_t)bc * TLEN;
    float*       oc = out + (size_t)bc * TLEN;
    for (int gi = gi0 + tid; gi < gi1; gi += NTHR) {
        int t   = gi * 4;
        int tau = t + PAD;
        int T   = tau >> 10;
        int u0  = tau & 1023;

        float mv[4];
        bool vd[4];
#pragma unroll
        for (int i = 0; i < 4; i++) {
            int f = T - i;
            vd[i] = (f >= 0) && (f < NFRM);
            mv[i] = (vd[i] && f >= flo) ? smask[f - flo] : 0.f;
        }

        float4 xv = *(const float4*)(xc + t);
        float r[4];
#pragma unroll
        for (int jj = 0; jj < 4; jj++) {
            float4 wq = wsq[u0 + jj];
            float ws[4] = {wq.x, wq.y, wq.z, wq.w};
            float s0 = 0.f, s1 = 0.f;
#pragma unroll
            for (int i = 0; i < 4; i++) {
                if (vd[i]) { s0 += ws[i]; s1 += mv[i] * ws[i]; }
            }
            float denom = (s0 > 1e-11f) ? s0 : 1.0f;
            r[jj] = s1 / denom;
        }
        float4 ov;
        ov.x = xv.x * r[0]; ov.y = xv.y * r[1];
        ov.z = xv.z * r[2]; ov.w = xv.w * r[3];
        *(float4*)(oc + t) = ov;
    }
}

// Phase O (fallback): vectorized masked OLA from global mask
__device__ __forceinline__ void phaseO(int gtid, int gstride,
                                       const float4* __restrict__ wsq,
                                       const float* __restrict__ x,
                                       const float* __restrict__ mask,
                                       float* __restrict__ out) {
    const int NG = (BATCH * 2 * TLEN) / 4;
    for (int gidx = gtid; gidx < NG; gidx += gstride) {
        int idx = gidx * 4;
        int t  = idx & (TLEN - 1);
        int bc = idx >> 18;
        int b  = bc >> 1;
        int tau = t + PAD;
        int T = tau >> 10;
        int u0 = tau & 1023;
        const float* mb = mask + b * NFRM;

        float mv[4];
        bool vd[4];
#pragma unroll
        for (int i = 0; i < 4; i++) {
            int f = T - i;
            vd[i] = (f >= 0) && (f < NFRM);
            mv[i] = vd[i] ? mb[f] : 0.f;
        }

        float4 xv = *(const float4*)(x + idx);
        float r[4];
#pragma unroll
        for (int jj = 0; jj < 4; jj++) {
            float4 wq = wsq[u0 + jj];
            float ws[4] = {wq.x, wq.y, wq.z, wq.w};
            float s0 = 0.f, s1 = 0.f;
#pragma unroll
            for (int i = 0; i < 4; i++) {
                if (vd[i]) { s0 += ws[i]; s1 += mv[i] * ws[i]; }
            }
            float denom = (s0 > 1e-11f) ? s0 : 1.0f;
            r[jj] = s1 / denom;
        }
        float4 ov;
        ov.x = xv.x * r[0]; ov.y = xv.y * r[1];
        ov.z = xv.z * r[2]; ov.w = xv.w * r[3];
        *(float4*)(out + idx) = ov;
    }
}

// =================== software grid barrier (persistent blocks) ======================
__device__ __forceinline__ void gbar(unsigned* bar, unsigned round) {
    __threadfence();                 // device-scope: prior writes visible
    __syncthreads();
    if (threadIdx.x == 0) {
        __hip_atomic_fetch_add(bar, 1u, __ATOMIC_ACQ_REL, __HIP_MEMORY_SCOPE_AGENT);
        unsigned target = round * GRID;
        while (__hip_atomic_load(bar, __ATOMIC_ACQUIRE, __HIP_MEMORY_SCOPE_AGENT) < target) {
            __builtin_amdgcn_s_sleep(2);
        }
    }
    __syncthreads();
}

// =================== mega kernel (persistent grid, 2 barriers) ======================
__global__ __launch_bounds__(NTHR, 4) void mega_kernel(const float* __restrict__ x,
                                                       const float* __restrict__ w1,
                                                       const float* __restrict__ b1,
                                                       const float* __restrict__ w2,
                                                       const float* __restrict__ b2,
                                                       const float* __restrict__ w3,
                                                       const float* __restrict__ b3,
                                                       unsigned int* __restrict__ Bwf,
                                                       unsigned short* __restrict__ xbf,
                                                       float* __restrict__ PC,
                                                       float* __restrict__ out,
                                                       unsigned* __restrict__ bar) {
    __shared__ __align__(16) float2 smem[4368];   // 34.9 KB; zb in D, Atile in M, wsq+smask in KO
    int blk = blockIdx.x;
    int tid = threadIdx.x;

    // Phase D on blocks 0..149; idle blocks 150..575 materialize bf16 padded x.
    if (blk < 150) phaseD<NTHR>(blk, tid, smem, w1, Bwf);
    else           phaseX((blk - 150) * NTHR + tid, (GRID - 150) * NTHR, x, xbf);
    gbar(bar, 1);

    phaseM(blk, tid, (unsigned int*)smem, xbf, Bwf, PC);
    gbar(bar, 2);

    phaseKO(blk, tid, smem, PC, b1, w2, b2, w3, b3, x, out);
}

// =================== fallback kernels (5-kernel chain, same math) ===================
__global__ __launch_bounds__(256) void xprep_kernel(const float* __restrict__ x,
                                                    unsigned short* __restrict__ xbf) {
    phaseX(blockIdx.x * 256 + threadIdx.x, gridDim.x * 256, x, xbf);
}
__global__ __launch_bounds__(256) void dfft_fused_kernel(const float* __restrict__ w1,
                                                         unsigned int* __restrict__ Bwf) {
    __shared__ __align__(16) float2 zb[4368];
    phaseD<256>(blockIdx.x, threadIdx.x, zb, w1, Bwf);
}
__global__ __launch_bounds__(320) void mlp_mfma_kernel(const unsigned short* __restrict__ xbf,
                                                       const unsigned int* __restrict__ Bwf,
                                                       float* __restrict__ PC) {
    __shared__ __align__(16) unsigned int Atile[2][2048];
    phaseM(blockIdx.x, threadIdx.x, &Atile[0][0], xbf, Bwf, PC);
}
__global__ __launch_bounds__(256) void mask_kernel(const float* __restrict__ PC,
                                                   const float* __restrict__ b1,
                                                   const float* __restrict__ w2,
                                                   const float* __restrict__ b2,
                                                   const float* __restrict__ w3,
                                                   const float* __restrict__ b3,
                                                   float* __restrict__ mask) {
    phaseK(blockIdx.x * 4 + (threadIdx.x >> 6), threadIdx.x & 63,
           PC, b1, w2, b2, w3, b3, mask);
}
__global__ __launch_bounds__(256) void ola_kernel(const float* __restrict__ x,
                                                  const float* __restrict__ mask,
                                                  float* __restrict__ out) {
    __shared__ __align__(16) float4 wsq[1024];
    buildWsq<256>(threadIdx.x, wsq);
    __syncthreads();
    phaseO(blockIdx.x * 256 + threadIdx.x, gridDim.x * 256, wsq, x, mask, out);
}

// ---------------- launch ----------------
extern "C" void kernel_launch(void* const* d_in, const int* in_sizes, int n_in,
                              void* d_out, int out_size, void* d_ws, size_t ws_size,
                              hipStream_t stream) {
    const float* x  = (const float*)d_in[0];
    const float* w1 = (const float*)d_in[1];
    const float* b1 = (const float*)d_in[2];
    const float* w2 = (const float*)d_in[3];
    const float* b2 = (const float*)d_in[4];
    const float* w3 = (const float*)d_in[5];
    const float* b3 = (const float*)d_in[6];

    char* wsp = (char*)d_ws;
    size_t off = 0;
    auto alloc = [&](size_t bytes) { void* p = wsp + off; off = (off + bytes + 511) & ~(size_t)511; return p; };

    unsigned int* Bwf    = (unsigned int*)alloc((size_t)NKS * 5 * 1024);           // 1.31 MB
    unsigned short* xbf  = (unsigned short*)alloc((size_t)16 * XPADL * 2);         // 9.57 MB
    float* PC            = (float*)alloc((size_t)KSPL * 8 * FPADR * NCOL * 4);     // 5.90 MB
    float* mask          = (float*)alloc((size_t)BATCH * NFRM * 4);
    unsigned* bar        = (unsigned*)alloc(512);
    float* out = (float*)d_out;

    // persistent-grid feasibility: need GRID blocks co-resident (deadlock-free guard)
    int maxB = 0, dev = 0, numCU = 0;
    hipGetDevice(&dev);
    hipDeviceGetAttribute(&numCU, hipDeviceAttributeMultiprocessorCount, dev);
    hipError_t qerr = hipOccupancyMaxActiveBlocksPerMultiprocessor(&maxB, mega_kernel, NTHR, 0);

    if (qerr == hipSuccess && numCU > 0 && (size_t)maxB * (size_t)numCU >= GRID) {
        hipMemsetAsync(bar, 0, 64, stream);
        mega_kernel<<<GRID, NTHR, 0, stream>>>(x, w1, b1, w2, b2, w3, b3,
                                               Bwf, xbf, PC, out, bar);
    } else {
        xprep_kernel<<<(16 * (XPADL / 8) + 255) / 256, 256, 0, stream>>>(x, xbf);
        dfft_fused_kernel<<<150, 256, 0, stream>>>(w1, Bwf);
        mlp_mfma_kernel<<<BATCH * 9 * KSPL, 320, 0, stream>>>(xbf, Bwf, PC);
        mask_kernel<<<(BATCH * NFRM + 3) / 4, 256, 0, stream>>>(PC, b1, w2, b2, w3, b3, mask);
        ola_kernel<<<(BATCH * 2 * TLEN + 1023) / 1024, 256, 0, stream>>>(x, mask, out);
    }
}